// Round 2
// baseline (58.240 us; speedup 1.0000x reference)
//
#include <hip/hip_runtime.h>

typedef __attribute__((ext_vector_type(8))) _Float16 half8;
typedef __attribute__((ext_vector_type(4))) _Float16 half4;
typedef __attribute__((ext_vector_type(4))) float f32x4;

// ---- constants from the reference ----
#define COS_M 0.98006657784124163f
#define SIN_M 0.19866933079506122f
#define TH_C  (-0.98006657784124163f)
#define MM_C  0.039733866159012244f
#define S_OVER_TEMP (10.0f / 0.07f)

// monotone-in-c transform: c -> S*phi(c)/TEMP  (loss invariant to stabilizer,
// so row-max of raw dots works as the stabilizer after this transform)
__device__ inline float xform(float c) {
  float s2 = fmaxf(1.0f - c * c, 0.0f);
  float sn = sqrtf(s2);
  float phi = c * COS_M - sn * SIN_M;
  float out = (c - TH_C > 0.0f) ? phi : (c - MM_C);
  return out * S_OVER_TEMP;
}

// ---------------- KA: fused row-normalize + G = cfn*cfn^T (f16 out) ------------
// 128x128 tile per block, 4 waves (2x2), each wave 64x64 = 4x4 frags of 16x16.
// Each block normalizes its own A/B row-tiles from feats (L3-resident, cheap).
// G is symmetric: store transposed so each lane's 4 acc elements are one 8B store.
__global__ __launch_bounds__(256) void k_gemm_fused(const float* __restrict__ feats,
                                                    _Float16* __restrict__ Gh,
                                                    float* __restrict__ out) {
  __shared__ alignas(16) _Float16 la[128 * 200];  // stride 200 (400B): 2-way alias = free
  __shared__ alignas(16) _Float16 lb[128 * 200];
  const int bm = blockIdx.x, bn = blockIdx.y;
  const int t = threadIdx.x;
  if (bm == 0 && bn == 0 && t == 0) out[0] = 0.0f;  // zero accumulator for KB

  // stage tile bt (128 rows of concat-order cf), l2-normalized, into lds
  auto stage = [&](int bt, _Float16* lds) {
    const int rr = t >> 1, h = t & 1;  // 2 threads per row, 96 floats each
    const int r = bt * 128 + rr;
    const float4* s4 =
        (const float4*)(feats + (size_t)((r & 1023) * 2 + (r >> 10)) * 192 + h * 96);
    float ss = 0.f;
#pragma unroll
    for (int q = 0; q < 24; ++q) {
      float4 v = s4[q];
      ss += v.x * v.x + v.y * v.y + v.z * v.z + v.w * v.w;
    }
    ss += __shfl_xor(ss, 1);
    const float inv = 1.0f / fmaxf(sqrtf(ss), 1e-12f);
    _Float16* dst = lds + rr * 200 + h * 96;
#pragma unroll
    for (int q = 0; q < 24; ++q) {
      float4 v = s4[q];  // second read: L1/L2 hot
      half4 o = {(_Float16)(v.x * inv), (_Float16)(v.y * inv),
                 (_Float16)(v.z * inv), (_Float16)(v.w * inv)};
      *(half4*)(dst + q * 4) = o;
    }
  };
  stage(bm, la);
  if (bn != bm) stage(bn, lb);
  __syncthreads();
  const _Float16* Bp = (bn == bm) ? la : lb;

  const int lane = t & 63;
  const int w = t >> 6;
  const int wr = w >> 1, wc = w & 1;  // 2x2 wave grid, 64x64 each
  const int lr = lane & 15, kg = lane >> 4;

  f32x4 acc[4][4];
#pragma unroll
  for (int m = 0; m < 4; ++m)
#pragma unroll
    for (int n = 0; n < 4; ++n) acc[m][n] = (f32x4){0.f, 0.f, 0.f, 0.f};

#pragma unroll
  for (int kc = 0; kc < 6; ++kc) {  // K = 192 = 6 * 32
    half8 af[4], bf[4];
    const int koff = kc * 32 + kg * 8;
#pragma unroll
    for (int m = 0; m < 4; ++m)
      af[m] = *(const half8*)&la[(wr * 64 + m * 16 + lr) * 200 + koff];
#pragma unroll
    for (int n = 0; n < 4; ++n)
      bf[n] = *(const half8*)&Bp[(wc * 64 + n * 16 + lr) * 200 + koff];
#pragma unroll
    for (int m = 0; m < 4; ++m)
#pragma unroll
      for (int n = 0; n < 4; ++n)
        acc[m][n] = __builtin_amdgcn_mfma_f32_16x16x32_f16(af[m], bf[n], acc[m][n], 0, 0, 0);
  }

  const int rb = bm * 128 + wr * 64;
  const int cb = bn * 128 + wc * 64;
#pragma unroll
  for (int m = 0; m < 4; ++m)
#pragma unroll
    for (int n = 0; n < 4; ++n) {
      const int r0 = rb + m * 16 + kg * 4;  // C/D: col=lane&15, row=(lane>>4)*4+e
      const int c0 = cb + n * 16 + lr;
      half4 o = {(_Float16)acc[m][n][0], (_Float16)acc[m][n][1],
                 (_Float16)acc[m][n][2], (_Float16)acc[m][n][3]};
      *(half4*)&Gh[(size_t)c0 * 2048 + r0] = o;  // transposed store (G symmetric)
    }
}

// ---------------- KB: per-row stats -> loss, atomic mean into out --------------
__global__ __launch_bounds__(256) void k_rowstats(const _Float16* __restrict__ Gh,
                                                  const int* __restrict__ labels,
                                                  float* __restrict__ out) {
  const int i = blockIdx.x;
  const int t = threadIdx.x;
  const int lane = t & 63, w = t >> 6;
  half8 v = *(const half8*)&Gh[(size_t)i * 2048 + t * 8];
  float gv[8];
#pragma unroll
  for (int u = 0; u < 8; ++u) gv[u] = (float)v[u];

  float ss = 0.f, mx = -3.4e38f;
#pragma unroll
  for (int u = 0; u < 8; ++u) { ss += gv[u] * gv[u]; mx = fmaxf(mx, gv[u]); }
#pragma unroll
  for (int o = 32; o; o >>= 1) {
    ss += __shfl_down(ss, o);
    mx = fmaxf(mx, __shfl_down(mx, o));
  }
  __shared__ float s4[4], m4[4];
  if (lane == 0) { s4[w] = ss; m4[w] = mx; }
  __syncthreads();
  const float sst = s4[0] + s4[1] + s4[2] + s4[3];
  const float gmax = fmaxf(fmaxf(m4[0], m4[1]), fmaxf(m4[2], m4[3]));
  const float invn = 1.0f / fmaxf(sqrtf(sst), 1e-12f);
  const float Mst = xform(gmax * invn);  // stabilizer (loss-invariant choice)

  const int base = (t * 8) & 1023;
  const int4 la0 = *(const int4*)&labels[base];
  const int4 la1 = *(const int4*)&labels[base + 4];
  const int labs[8] = {la0.x, la0.y, la0.z, la0.w, la1.x, la1.y, la1.z, la1.w};
  const int mylab = labels[i & 1023];

  float es = 0.f, ps = 0.f, cn = 0.f;
#pragma unroll
  for (int u = 0; u < 8; ++u) {
    const int j = t * 8 + u;
    const float l = xform(gv[u] * invn) - Mst;
    if (j != i) {
      es += expf(l);
      if (labs[u] == mylab) { ps += l; cn += 1.f; }
    }
  }
#pragma unroll
  for (int o = 32; o; o >>= 1) {
    es += __shfl_down(es, o);
    ps += __shfl_down(ps, o);
    cn += __shfl_down(cn, o);
  }
  __shared__ float e4[4], p4[4], c4[4];
  if (lane == 0) { e4[w] = es; p4[w] = ps; c4[w] = cn; }
  __syncthreads();
  if (t == 0) {
    const float E = e4[0] + e4[1] + e4[2] + e4[3];
    const float P = p4[0] + p4[1] + p4[2] + p4[3];
    const float C = c4[0] + c4[1] + c4[2] + c4[3];
    atomicAdd(out, -(P / C - logf(E)) * (1.0f / 2048.0f));
  }
}

extern "C" void kernel_launch(void* const* d_in, const int* in_sizes, int n_in,
                              void* d_out, int out_size, void* d_ws, size_t ws_size,
                              hipStream_t stream) {
  const float* feats = (const float*)d_in[0];
  const int* labels = (const int*)d_in[1];
  // d_in[2]/d_in[3] (fc_w/fc_b) are provably dead: atten == 1.0 exactly

  _Float16* Gh = (_Float16*)d_ws;  // 2048*2048*2 = 8 MiB

  dim3 g2(16, 16);
  k_gemm_fused<<<g2, 256, 0, stream>>>(feats, Gh, (float*)d_out);
  k_rowstats<<<2048, 256, 0, stream>>>(Gh, labels, (float*)d_out);
}

// Round 3
// 43.206 us; speedup vs baseline: 1.3480x; 1.3480x over previous
//
#include <hip/hip_runtime.h>

typedef __attribute__((ext_vector_type(8))) _Float16 half8;
typedef __attribute__((ext_vector_type(4))) _Float16 half4;
typedef __attribute__((ext_vector_type(4))) float f32x4;

// ---- constants from the reference ----
#define COS_M 0.98006657784124163f
#define SIN_M 0.19866933079506122f
#define TH_C  (-0.98006657784124163f)
#define MM_C  0.039733866159012244f
#define S_OVER_TEMP (10.0f / 0.07f)

// monotone-in-c transform: c -> S*phi(c)/TEMP (loss invariant to stabilizer
// choice, so xform(rowmax) works as the log-sum-exp stabilizer)
__device__ inline float xform(float c) {
  float s2 = fmaxf(1.0f - c * c, 0.0f);
  float sn = sqrtf(s2);
  float phi = c * COS_M - sn * SIN_M;
  float out = (c - TH_C > 0.0f) ? phi : (c - MM_C);
  return out * S_OVER_TEMP;
}

// ---------------- K1: cf = l2norm rows of concat(views) -> f16 ----------------
__global__ __launch_bounds__(64) void k_normalize(const float* __restrict__ feats,
                                                  _Float16* __restrict__ cfn,
                                                  float* __restrict__ out) {
  const int i = blockIdx.x;  // row in [0, 2048)
  if (i == 0 && threadIdx.x == 0) out[0] = 0.0f;  // zero accum for K3 (stream-ordered)
  const int b = i & 1023, v = i >> 10;
  const float* src = feats + ((size_t)b * 2 + v) * 192;
  const int t = threadIdx.x;
  float x0 = src[t], x1 = src[t + 64], x2 = src[t + 128];
  float ss = x0 * x0 + x1 * x1 + x2 * x2;
#pragma unroll
  for (int o = 32; o; o >>= 1) ss += __shfl_down(ss, o);
  ss = __shfl(ss, 0);
  float inv = 1.0f / fmaxf(sqrtf(ss), 1e-12f);
  _Float16* dst = cfn + (size_t)i * 192;
  dst[t]       = (_Float16)(x0 * inv);
  dst[t + 64]  = (_Float16)(x1 * inv);
  dst[t + 128] = (_Float16)(x2 * inv);
}

// ---------------- K2: G = cfn * cfn^T -> f16 (transposed store; G symmetric) --
// 128x128 tile per block, 4 waves (2x2), each wave 64x64 = 4x4 frags of 16x16.
__global__ __launch_bounds__(256) void k_gemm(const _Float16* __restrict__ cfn,
                                              _Float16* __restrict__ Gh) {
  __shared__ alignas(16) _Float16 la[128 * 200];  // stride 200 (400B): 2-way alias = free
  __shared__ alignas(16) _Float16 lb[128 * 200];
  const int bm = blockIdx.x, bn = blockIdx.y;
  const uint4* srcA = (const uint4*)(cfn + (size_t)bm * 128 * 192);
  const uint4* srcB = (const uint4*)(cfn + (size_t)bn * 128 * 192);
  for (int idx = threadIdx.x; idx < 3072; idx += 256) {  // 128 rows * 24 uint4/row
    int r = idx / 24, c = idx - r * 24;
    *(uint4*)&la[r * 200 + c * 8] = srcA[idx];
    *(uint4*)&lb[r * 200 + c * 8] = srcB[idx];
  }
  __syncthreads();

  const int lane = threadIdx.x & 63;
  const int w = threadIdx.x >> 6;
  const int wr = w >> 1, wc = w & 1;  // 2x2 wave grid, 64x64 each
  const int lr = lane & 15, kg = lane >> 4;

  f32x4 acc[4][4];
#pragma unroll
  for (int m = 0; m < 4; ++m)
#pragma unroll
    for (int n = 0; n < 4; ++n) acc[m][n] = (f32x4){0.f, 0.f, 0.f, 0.f};

#pragma unroll
  for (int kc = 0; kc < 6; ++kc) {  // K = 192 = 6 * 32
    half8 af[4], bf[4];
    const int koff = kc * 32 + kg * 8;
#pragma unroll
    for (int m = 0; m < 4; ++m)
      af[m] = *(const half8*)&la[(wr * 64 + m * 16 + lr) * 200 + koff];
#pragma unroll
    for (int n = 0; n < 4; ++n)
      bf[n] = *(const half8*)&lb[(wc * 64 + n * 16 + lr) * 200 + koff];
#pragma unroll
    for (int m = 0; m < 4; ++m)
#pragma unroll
      for (int n = 0; n < 4; ++n)
        acc[m][n] = __builtin_amdgcn_mfma_f32_16x16x32_f16(af[m], bf[n], acc[m][n], 0, 0, 0);
  }

  const int rb = bm * 128 + wr * 64;
  const int cb = bn * 128 + wc * 64;
#pragma unroll
  for (int m = 0; m < 4; ++m)
#pragma unroll
    for (int n = 0; n < 4; ++n) {
      const int r0 = rb + m * 16 + kg * 4;  // C/D: col=lane&15, row=(lane>>4)*4+e
      const int c0 = cb + n * 16 + lr;
      half4 o = {(_Float16)acc[m][n][0], (_Float16)acc[m][n][1],
                 (_Float16)acc[m][n][2], (_Float16)acc[m][n][3]};
      *(half4*)&Gh[(size_t)c0 * 2048 + r0] = o;  // transposed store (G symmetric)
    }
}

// ---------------- K3: 8 rows per block -> partial mean, 1 atomic/block --------
__global__ __launch_bounds__(256) void k_rowloss(const _Float16* __restrict__ Gh,
                                                 const int* __restrict__ labels,
                                                 float* __restrict__ out) {
  const int t = threadIdx.x;
  const int lane = t & 63, w = t >> 6;

  // per-thread label slice (same j's every row pass), loaded once
  const int base = (t * 8) & 1023;
  const int4 la0 = *(const int4*)&labels[base];
  const int4 la1 = *(const int4*)&labels[base + 4];
  const int labs[8] = {la0.x, la0.y, la0.z, la0.w, la1.x, la1.y, la1.z, la1.w};

  __shared__ float s4[4], m4[4], e4[4], p4[4], c4[4];
  float lsum = 0.0f;

  for (int rr = 0; rr < 8; ++rr) {
    const int i = blockIdx.x * 8 + rr;
    half8 v = *(const half8*)&Gh[(size_t)i * 2048 + t * 8];
    float gv[8];
#pragma unroll
    for (int u = 0; u < 8; ++u) gv[u] = (float)v[u];

    float ss = 0.f, mx = -3.4e38f;
#pragma unroll
    for (int u = 0; u < 8; ++u) { ss += gv[u] * gv[u]; mx = fmaxf(mx, gv[u]); }
#pragma unroll
    for (int o = 32; o; o >>= 1) {
      ss += __shfl_down(ss, o);
      mx = fmaxf(mx, __shfl_down(mx, o));
    }
    if (lane == 0) { s4[w] = ss; m4[w] = mx; }
    __syncthreads();
    const float sst = s4[0] + s4[1] + s4[2] + s4[3];
    const float gmax = fmaxf(fmaxf(m4[0], m4[1]), fmaxf(m4[2], m4[3]));
    const float invn = 1.0f / fmaxf(sqrtf(sst), 1e-12f);
    const float Mst = xform(gmax * invn);  // stabilizer (loss-invariant choice)
    const int mylab = labels[i & 1023];

    float es = 0.f, ps = 0.f, cn = 0.f;
#pragma unroll
    for (int u = 0; u < 8; ++u) {
      const int j = t * 8 + u;
      const float l = xform(gv[u] * invn) - Mst;
      if (j != i) {
        es += expf(l);
        if (labs[u] == mylab) { ps += l; cn += 1.f; }
      }
    }
#pragma unroll
    for (int o = 32; o; o >>= 1) {
      es += __shfl_down(es, o);
      ps += __shfl_down(ps, o);
      cn += __shfl_down(cn, o);
    }
    if (lane == 0) { e4[w] = es; p4[w] = ps; c4[w] = cn; }
    __syncthreads();
    if (t == 0) {
      const float E = e4[0] + e4[1] + e4[2] + e4[3];
      const float P = p4[0] + p4[1] + p4[2] + p4[3];
      const float C = c4[0] + c4[1] + c4[2] + c4[3];
      lsum += -(P / C - logf(E));
    }
  }
  if (t == 0) atomicAdd(out, lsum * (1.0f / 2048.0f));
}

extern "C" void kernel_launch(void* const* d_in, const int* in_sizes, int n_in,
                              void* d_out, int out_size, void* d_ws, size_t ws_size,
                              hipStream_t stream) {
  const float* feats = (const float*)d_in[0];
  const int* labels = (const int*)d_in[1];
  // d_in[2]/d_in[3] (fc_w/fc_b) are provably dead: atten == 1.0 exactly

  char* ws = (char*)d_ws;
  _Float16* cfn = (_Float16*)ws;             // 2048*192*2  = 768 KiB
  _Float16* Gh  = (_Float16*)(ws + 786432);  // 2048*2048*2 = 8 MiB

  k_normalize<<<2048, 64, 0, stream>>>(feats, cfn, (float*)d_out);
  dim3 g2(16, 16);
  k_gemm<<<g2, 256, 0, stream>>>(cfn, Gh);
  k_rowloss<<<256, 256, 0, stream>>>(Gh, labels, (float*)d_out);
}